// Round 7
// baseline (412.670 us; speedup 1.0000x reference)
//
#include <hip/hip_runtime.h>

#define EMB   1024
#define SEQ   2048
#define BATCH 4
#define HEADS 16
#define HDIM  64
#define MTOT  8192

typedef __bf16 bf16x8 __attribute__((ext_vector_type(8)));
typedef float  fx4    __attribute__((ext_vector_type(4)));

#if __has_builtin(__builtin_amdgcn_exp2f)
#define EXP2(x) __builtin_amdgcn_exp2f(x)
#else
#define EXP2(x) exp2f(x)
#endif

__device__ __forceinline__ unsigned short f2bf(float f) {
    unsigned u = __builtin_bit_cast(unsigned, f);
    u += 0x7fffu + ((u >> 16) & 1u);   // RNE
    return (unsigned short)(u >> 16);
}
__device__ __forceinline__ unsigned short bfbits(float f) {
    __bf16 h = (__bf16)f;
    return __builtin_bit_cast(unsigned short, h);
}

#define AS1 __attribute__((address_space(1)))
#define AS3 __attribute__((address_space(3)))
__device__ __forceinline__ void glds16(const void* g, void* l) {
    __builtin_amdgcn_global_load_lds((AS1 void*)g, (AS3 void*)l, 16, 0, 0);
}
// vmcnt(0) drain. REQUIRED before the barrier that publishes global_load_lds
// data (round-4 race: compiler does not reliably drain LDS-DMA vmcnt at
// s_barrier when the glds was issued far upstream).
#define DRAIN_GLDS() __builtin_amdgcn_s_waitcnt(0x0f70)

// log2(e)/32 — folded into Q so softmax is exp2(s) with no further scaling.
#define QSCALE 0.0450842137604569f

// ---------------------------------------------------------------------------
// x [8192x1024] fp32 -> bf16
// ---------------------------------------------------------------------------
__global__ __launch_bounds__(256) void cvt_x_kernel(const float* __restrict__ x,
                                                    unsigned short* __restrict__ xb)
{
    const int idx = (blockIdx.x * 256 + threadIdx.x) * 4;
    const float4 v = *(const float4*)(x + idx);
    ushort4 o;
    o.x = f2bf(v.x); o.y = f2bf(v.y); o.z = f2bf(v.z); o.w = f2bf(v.w);
    *(ushort4*)(xb + idx) = o;
}

// ---------------------------------------------------------------------------
// W [K][N] fp32 -> Wt [N][K] bf16 (transpose), 4 matrices via grid.z
// ---------------------------------------------------------------------------
__global__ __launch_bounds__(256) void cvt_w_kernel(
    const float* __restrict__ w0, const float* __restrict__ w1,
    const float* __restrict__ w2, const float* __restrict__ w3,
    unsigned short* __restrict__ o0, unsigned short* __restrict__ o1,
    unsigned short* __restrict__ o2, unsigned short* __restrict__ o3)
{
    const int z = blockIdx.z;
    const float* W = z == 0 ? w0 : (z == 1 ? w1 : (z == 2 ? w2 : w3));
    unsigned short* O = z == 0 ? o0 : (z == 1 ? o1 : (z == 2 ? o2 : o3));

    __shared__ float Ws[64][65];
    const int t  = threadIdx.x;
    const int k0 = blockIdx.x * 64, n0 = blockIdx.y * 64;
#pragma unroll
    for (int p = 0; p < 4; ++p) {
        const int row = p * 16 + (t >> 4);
        const int col = (t & 15) * 4;
        const float4 v = *(const float4*)(W + (size_t)(k0 + row) * EMB + n0 + col);
        Ws[row][col]     = v.x; Ws[row][col + 1] = v.y;
        Ws[row][col + 2] = v.z; Ws[row][col + 3] = v.w;
    }
    __syncthreads();
    const int nn = t >> 2;
    const int kb = (t & 3) * 16;
#pragma unroll
    for (int q = 0; q < 2; ++q) {
        const int kk = kb + q * 8;
        ushort4 u0, u1;
        u0.x = f2bf(Ws[kk + 0][nn]); u0.y = f2bf(Ws[kk + 1][nn]);
        u0.z = f2bf(Ws[kk + 2][nn]); u0.w = f2bf(Ws[kk + 3][nn]);
        u1.x = f2bf(Ws[kk + 4][nn]); u1.y = f2bf(Ws[kk + 5][nn]);
        u1.z = f2bf(Ws[kk + 6][nn]); u1.w = f2bf(Ws[kk + 7][nn]);
        *(ushort4*)(O + (size_t)(n0 + nn) * EMB + k0 + kk)     = u0;
        *(ushort4*)(O + (size_t)(n0 + nn) * EMB + k0 + kk + 4) = u1;
    }
}

// ---------------------------------------------------------------------------
// bf16 MFMA GEMM, BK=64 (16 k-iters: half the barrier/drain count of BK=32).
// A/B-swapped epilogue (lane holds 4 consecutive e). XOR chunk swizzle on the
// global side: lane fetches chunk (lane&7)^(row&7); frag reads un-swizzle
// with (h*4+quad)^(low4&7) — conflict-free unpadded LDS.
// mode 0: z= Q/K/V. Q -> [B,H,N,D]*QSCALE; K -> [B,H,N,D];
//         V -> [B,H,D,N], kv permuted per 64-block: np = (n%16)*4 + (n/16)%4.
// mode 1: fp32 out [M][E].
// ---------------------------------------------------------------------------
__global__ __launch_bounds__(256) void gemm_bf16_kernel(
    const unsigned short* __restrict__ Ag,
    const unsigned short* __restrict__ B0, const unsigned short* __restrict__ B1,
    const unsigned short* __restrict__ B2,
    const float* __restrict__ bias0, const float* __restrict__ bias1,
    const float* __restrict__ bias2,
    void* out0, void* out1, void* out2, int mode)
{
    const int z = blockIdx.z;
    const unsigned short* __restrict__ Bg = z == 0 ? B0 : (z == 1 ? B1 : B2);
    const float* __restrict__ bias = z == 0 ? bias0 : (z == 1 ? bias1 : bias2);
    void* outp = z == 0 ? out0 : (z == 1 ? out1 : out2);

    __shared__ unsigned short As[128][64];   // x rows   (chunk-swizzled)
    __shared__ unsigned short Bs[128][64];   // W rows   (chunk-swizzled)

    const int t    = threadIdx.x;
    const int w    = t >> 6;
    const int lane = t & 63;
    const int low4 = lane & 15;
    const int quad = lane >> 4;
    const int m0 = blockIdx.x * 128;
    const int e0 = blockIdx.y * 128;
    const int we = (w & 1) * 64;     // e-offset of this wave
    const int wm = (w >> 1) * 64;    // m-offset of this wave

    const int srow8 = lane >> 3;                    // row within 8-row group
    const int scg   = ((lane & 7) ^ srow8) * 8;     // swizzled global chunk
    const int x7    = low4 & 7;                     // frag un-swizzle key

    fx4 acc[4][4] = {};   // [i: e-subtile][j: m-subtile]

    for (int k0 = 0; k0 < EMB; k0 += 64) {
        __syncthreads();
#pragma unroll
        for (int g = 0; g < 4; ++g) {
            const int r = w * 32 + g * 8;
            glds16(Ag + (size_t)(m0 + r + srow8) * EMB + k0 + scg, &As[r][0]);
            glds16(Bg + (size_t)(e0 + r + srow8) * EMB + k0 + scg, &Bs[r][0]);
        }
        DRAIN_GLDS();
        __syncthreads();

#pragma unroll
        for (int h = 0; h < 2; ++h) {
            const int fc = ((h * 4 + quad) ^ x7) * 8;
            bf16x8 af[4], bfr[4];
#pragma unroll
            for (int i = 0; i < 4; ++i) {
                af[i]  = *(const bf16x8*)&Bs[we + i * 16 + low4][fc];  // A = W
                bfr[i] = *(const bf16x8*)&As[wm + i * 16 + low4][fc];  // B = x
            }
#pragma unroll
            for (int i = 0; i < 4; ++i)
#pragma unroll
                for (int j = 0; j < 4; ++j)
                    acc[i][j] = __builtin_amdgcn_mfma_f32_16x16x32_bf16(af[i], bfr[j], acc[i][j], 0, 0, 0);
        }
    }

    // bias: e = e0 + we + i*16 + quad*4 + rr  (4 consecutive)
    fx4 bv[4];
#pragma unroll
    for (int i = 0; i < 4; ++i)
        bv[i] = *(const fx4*)(bias + e0 + we + i * 16 + quad * 4);

    if (mode == 1) {
#pragma unroll
        for (int i = 0; i < 4; ++i)
#pragma unroll
            for (int j = 0; j < 4; ++j) {
                const int m  = m0 + wm + j * 16 + low4;
                const int eb = e0 + we + i * 16 + quad * 4;
                fx4 o4;
#pragma unroll
                for (int rr = 0; rr < 4; ++rr) o4[rr] = acc[i][j][rr] + bv[i][rr];
                *(fx4*)((float*)outp + (size_t)m * EMB + eb) = o4;
            }
    } else if (z <= 1) {
        const float sc = (z == 0) ? QSCALE : 1.0f;
        unsigned short* o = (unsigned short*)outp;
#pragma unroll
        for (int i = 0; i < 4; ++i)
#pragma unroll
            for (int j = 0; j < 4; ++j) {
                const int m  = m0 + wm + j * 16 + low4;
                const int eb = e0 + we + i * 16 + quad * 4;
                const int bb = m >> 11, n = m & (SEQ - 1);
                const int hh = eb >> 6, db = eb & 63;
                ushort4 o4;
                o4.x = f2bf((acc[i][j][0] + bv[i][0]) * sc);
                o4.y = f2bf((acc[i][j][1] + bv[i][1]) * sc);
                o4.z = f2bf((acc[i][j][2] + bv[i][2]) * sc);
                o4.w = f2bf((acc[i][j][3] + bv[i][3]) * sc);
                *(ushort4*)(o + (((size_t)(bb * HEADS + hh)) * SEQ + n) * HDIM + db) = o4;
            }
    } else {
        // V: the four j-subtiles give 4 consecutive permuted columns
        unsigned short* o = (unsigned short*)outp;
        const int mbase = m0 + wm;
        const int bb    = mbase >> 11;
        const int nb    = mbase & (SEQ - 1);
#pragma unroll
        for (int i = 0; i < 4; ++i) {
            const int eb = e0 + we + i * 16 + quad * 4;
            const int hh = eb >> 6, db = eb & 63;
#pragma unroll
            for (int rr = 0; rr < 4; ++rr) {
                ushort4 o4;
                o4.x = f2bf(acc[i][0][rr] + bv[i][rr]);
                o4.y = f2bf(acc[i][1][rr] + bv[i][rr]);
                o4.z = f2bf(acc[i][2][rr] + bv[i][rr]);
                o4.w = f2bf(acc[i][3][rr] + bv[i][rr]);
                *(ushort4*)(o + (((size_t)(bb * HEADS + hh)) * HDIM + db + rr) * SEQ
                              + nb + low4 * 4) = o4;
            }
        }
    }
}

// ---------------------------------------------------------------------------
// MFMA flash attention v5:
//  - K fragments DIRECT from global (coalesced 64B row-segments, L1/L2 hot)
//  - V via dbuf glds LDS staging (explicit vmcnt drain + barrier)
//  - shared per-wave Ps (round-6 slicing was neutral; 9 KB not 36 KB)
//  - LDS 25.2 KB; __launch_bounds__(256,3) targets 3 waves/SIMD
//  - XCD-locality: 1-D grid, bh = id%64 so the 8 q-blocks of a head land on
//    one XCD (dispatch round-robin id%8 == bh%8) -> K/V fetched once per XCD
// Wave = 64 q-rows; block = 4 waves = 256 q-rows. Grid 512.
// Q,K: [B,H,N,D] bf16; V: [B,H,D,N] bf16 (kv permuted per 64-block).
// ---------------------------------------------------------------------------
__global__ __launch_bounds__(256, 3) void attn_mfma5_kernel(
    const unsigned short* __restrict__ qg, const unsigned short* __restrict__ kg,
    const unsigned short* __restrict__ vg, unsigned short* __restrict__ attb)
{
    __shared__ unsigned short Vs[2][64][64];   // [buf][d][kv'], chunk-swizzled
    __shared__ unsigned short Ps[4][16][72];   // per-wave P [q][kv'], stride 72

    const int t    = threadIdx.x;
    const int w    = t >> 6;
    const int lane = t & 63;
    const int low4 = lane & 15;
    const int quad = lane >> 4;
    const int id   = blockIdx.x;
    const int bh   = id & 63;
    const int qblk = id >> 6;
    const int q0   = qblk * 256 + w * 64;
    const size_t base = (size_t)bh * SEQ * HDIM;

    const int srow8  = lane >> 3;                    // 0..7 within 8-row group
    const int schunk = (lane & 7) ^ srow8;           // swizzled 16B chunk
    const int x7     = low4 & 7;

    // resident Q A-fragments: 4 sub-tiles of 16 q-rows
    bf16x8 aq[4][2];
#pragma unroll
    for (int s = 0; s < 4; ++s) {
        const size_t qrow = base + (size_t)(q0 + s * 16 + low4) * HDIM;
        aq[s][0] = *(const bf16x8*)(qg + qrow + quad * 8);
        aq[s][1] = *(const bf16x8*)(qg + qrow + 32 + quad * 8);
    }

    fx4 o_acc[4][4] = {};
    float l_i[4][4] = {};
    const fx4 fzero = {0.f, 0.f, 0.f, 0.f};

    // prologue: stage V tile 0 into buf 0
    {
        const unsigned short* vp = vg + base + (size_t)(w * 16 + srow8) * SEQ + schunk * 8;
        glds16(vp,           &Vs[0][w * 16][0]);
        glds16(vp + 8 * SEQ, &Vs[0][w * 16 + 8][0]);
    }

    for (int tt0 = 0; tt0 < SEQ / 64; ++tt0) {
        const int buf = tt0 & 1;
        const int kv0 = tt0 * 64;
        DRAIN_GLDS();      // drain this wave's in-flight glds (round-4 fix)
        __syncthreads();   // rendezvous: all waves' V DMA now in LDS

        // K fragments direct from global (issue early; L1/L2-resident)
        bf16x8 kf[4][2];
#pragma unroll
        for (int tk = 0; tk < 4; ++tk) {
            const size_t krow = base + (size_t)(kv0 + tk * 16 + low4) * HDIM;
            kf[tk][0] = *(const bf16x8*)(kg + krow + quad * 8);
            kf[tk][1] = *(const bf16x8*)(kg + krow + 32 + quad * 8);
        }

        // V fragments from LDS (unswizzle: chunk = (c*4+quad) ^ (low4&7))
        bf16x8 vf[4][2];
#pragma unroll
        for (int t2 = 0; t2 < 4; ++t2) {
            const int row = t2 * 16 + low4;
#pragma unroll
            for (int c = 0; c < 2; ++c) {
                const int lc = (c * 4 + quad) ^ x7;
                vf[t2][c] = *(const bf16x8*)&Vs[buf][row][lc * 8];
            }
        }

        // prefetch next V tile into other buffer (overlaps compute below)
        if (tt0 + 1 < SEQ / 64) {
            const unsigned short* vp = vg + base + (size_t)(w * 16 + srow8) * SEQ
                                     + (kv0 + 64) + schunk * 8;
            glds16(vp,           &Vs[buf ^ 1][w * 16][0]);
            glds16(vp + 8 * SEQ, &Vs[buf ^ 1][w * 16 + 8][0]);
        }

#pragma unroll
        for (int s = 0; s < 4; ++s) {
            // S = Q K^T
            fx4 sa[4];
#pragma unroll
            for (int tk = 0; tk < 4; ++tk) {
                sa[tk] = __builtin_amdgcn_mfma_f32_16x16x32_bf16(aq[s][0], kf[tk][0], fzero, 0, 0, 0);
                sa[tk] = __builtin_amdgcn_mfma_f32_16x16x32_bf16(aq[s][1], kf[tk][1], sa[tk], 0, 0, 0);
            }
            // P = exp2(S); store (kv' = low4*4 + tk matches V permute)
#pragma unroll
            for (int r = 0; r < 4; ++r) {
                const float p0 = EXP2(sa[0][r]);
                const float p1 = EXP2(sa[1][r]);
                const float p2 = EXP2(sa[2][r]);
                const float p3 = EXP2(sa[3][r]);
                l_i[s][r] += (p0 + p1) + (p2 + p3);
                uint2 pk;
                pk.x = (unsigned)bfbits(p0) | ((unsigned)bfbits(p1) << 16);
                pk.y = (unsigned)bfbits(p2) | ((unsigned)bfbits(p3) << 16);
                *(uint2*)&Ps[w][quad * 4 + r][low4 * 4] = pk;
            }
            __asm__ volatile("" ::: "memory");
            // O += P V  (intra-wave in-order DS: write->read safe, no barrier)
            bf16x8 pf0 = *(const bf16x8*)&Ps[w][low4][quad * 8];
            bf16x8 pf1 = *(const bf16x8*)&Ps[w][low4][32 + quad * 8];
#pragma unroll
            for (int t2 = 0; t2 < 4; ++t2) {
                o_acc[s][t2] = __builtin_amdgcn_mfma_f32_16x16x32_bf16(pf0, vf[t2][0], o_acc[s][t2], 0, 0, 0);
                o_acc[s][t2] = __builtin_amdgcn_mfma_f32_16x16x32_bf16(pf1, vf[t2][1], o_acc[s][t2], 0, 0, 0);
            }
        }
    }

    // final l reduction across the 16 lanes of each quad-row group
#pragma unroll
    for (int s = 0; s < 4; ++s)
#pragma unroll
        for (int r = 0; r < 4; ++r) {
            float v = l_i[s][r];
            for (int off = 1; off < 16; off <<= 1)
                v += __shfl_xor(v, off, 16);
            l_i[s][r] = 1.0f / v;
        }

    // epilogue: merge heads -> att [B*N][EMB] bf16
    const int bb = bh >> 4, hh = bh & 15;
#pragma unroll
    for (int s = 0; s < 4; ++s)
#pragma unroll
        for (int r = 0; r < 4; ++r) {
            const size_t m = (size_t)bb * SEQ + q0 + s * 16 + quad * 4 + r;
#pragma unroll
            for (int t2 = 0; t2 < 4; ++t2) {
                const int e = hh * HDIM + t2 * 16 + low4;
                attb[m * EMB + e] = bfbits(o_acc[s][t2][r] * l_i[s][r]);
            }
        }
}

extern "C" void kernel_launch(void* const* d_in, const int* in_sizes, int n_in,
                              void* d_out, int out_size, void* d_ws, size_t ws_size,
                              hipStream_t stream)
{
    const float* x  = (const float*)d_in[0];
    const float* Wq = (const float*)d_in[1];
    const float* bq = (const float*)d_in[2];
    const float* Wk = (const float*)d_in[3];
    const float* bk = (const float*)d_in[4];
    const float* Wv = (const float*)d_in[5];
    const float* bv = (const float*)d_in[6];
    const float* Wo = (const float*)d_in[7];
    const float* bo = (const float*)d_in[8];

    unsigned short* ws  = (unsigned short*)d_ws;
    unsigned short* xb  = ws;                  // 8388608
    unsigned short* wqt = xb + 8388608;        // 1048576 each
    unsigned short* wkt = wqt + 1048576;
    unsigned short* wvt = wkt + 1048576;
    unsigned short* wot = wvt + 1048576;
    unsigned short* qb  = wot + 1048576;       // 8388608 each
    unsigned short* kbuf = qb + 8388608;
    unsigned short* vtb  = kbuf + 8388608;
    unsigned short* attb = vtb + 8388608;

    cvt_x_kernel<<<8192, 256, 0, stream>>>(x, xb);
    cvt_w_kernel<<<dim3(16, 16, 4), 256, 0, stream>>>(Wq, Wk, Wv, Wo, wqt, wkt, wvt, wot);

    gemm_bf16_kernel<<<dim3(64, 8, 3), 256, 0, stream>>>(
        xb, wqt, wkt, wvt, bq, bk, bv, qb, kbuf, vtb, 0);

    attn_mfma5_kernel<<<512, 256, 0, stream>>>(qb, kbuf, vtb, attb);

    gemm_bf16_kernel<<<dim3(64, 8, 1), 256, 0, stream>>>(
        attb, wot, wot, wot, bo, bo, bo, d_out, d_out, d_out, 1);
}